// Round 7
// baseline (310.773 us; speedup 1.0000x reference)
//
#include <hip/hip_runtime.h>
#include <math.h>

// Problem constants
#define NS      32768           // N_SAMPLES
#define M       16384           // NS/2, packed complex FFT length = 4^7
#define NEV     16
#define NB      64
#define T2      1024            // threads for FFT kernels (16 waves)

// LDS pad: break power-of-4 strides (incl. 1024/4096 from digit-reversal scatter)
__device__ __forceinline__ int ldsIdx(int i) { return i + (i >> 5) + (i >> 10); }
#define LDS_ELEMS (M + M / 32 + M / 1024)   // 16912 float2 = 135296 B < 160 KB

__device__ __forceinline__ float2 cmul(float2 a, float2 b) {
    return make_float2(a.x * b.x - a.y * b.y, a.x * b.y + a.y * b.x);
}

// reverse 7 base-4 digits (14 bits)
__device__ __forceinline__ int rev4_14(int i) {
    int r = 0;
#pragma unroll
    for (int d = 0; d < 7; ++d) { r = (r << 2) | (i & 3); i >>= 2; }
    return r;
}

// e^{-i*2*pi*k*s/NS}, s = si + sf (integer + fraction), exact integer mod
__device__ __forceinline__ float2 shift_phase(int k, int si, float sf) {
    unsigned ksi = ((unsigned)k * (unsigned)si) & (unsigned)(NS - 1);
    float total = (float)ksi + (float)k * sf;
    float f = total * (1.0f / (float)NS);
    f -= floorf(f);
    float ang = -6.28318530717958647692f * f;
    float sv, cv;
    __sincosf(ang, &sv, &cv);
    return make_float2(cv, sv);
}

// e^{-2*pi*i*k/NS}
__device__ __forceinline__ float2 wNS(int k) {
    float ang = (float)k * (-6.28318530717958647692f / (float)NS);
    float sv, cv;
    __sincosf(ang, &sv, &cv);
    return make_float2(cv, sv);
}

// In-place radix-4 DIT FFT of M=4^7 points in LDS; input must already be
// digit-reversed, output natural order. SIGN=-1 forward, SIGN=+1 inverse
// (unscaled). Twiddle hoisting: for stages t<6, j = (tid + it*1024)&(q-1) =
// tid&(q-1) is iteration-invariant (1024 % q == 0) -> one sincos per stage.
// Stage 6 advances j by 1024 per iteration -> incremental rotation by the
// constant e^{SIGN*i*pi/8} (cmuls, no sincos in the loop).
template <int SIGN>
__device__ void fft_lds(float2* lds, int tid) {
#pragma unroll
    for (int t = 0; t < 7; ++t) {
        const int q = 1 << (2 * t);
        const float c = (SIGN < 0 ? -6.28318530717958647692f
                                  :  6.28318530717958647692f) / (float)(4 * q);
        float2 w1, w2, w3, wstep;
        {
            float sv, cv;
            if (t < 6) {
                __sincosf(c * (float)(tid & (q - 1)), &sv, &cv);
                w1 = make_float2(cv, sv);
            } else {
                __sincosf(c * (float)tid, &sv, &cv);
                w1 = make_float2(cv, sv);
                __sincosf(c * 1024.0f, &sv, &cv);
                wstep = make_float2(cv, sv);
            }
            w2 = cmul(w1, w1);
            w3 = cmul(w2, w1);
        }
#pragma unroll
        for (int it = 0; it < (M / 4) / T2; ++it) {
            const int bf = tid + it * T2;
            const int g = bf >> (2 * t);
            const int j = bf & (q - 1);
            const int base = (g << (2 * t + 2)) + j;
            const int I0 = ldsIdx(base);
            const int I1 = ldsIdx(base + q);
            const int I2 = ldsIdx(base + 2 * q);
            const int I3 = ldsIdx(base + 3 * q);
            float2 a0 = lds[I0];
            float2 a1 = lds[I1];
            float2 a2 = lds[I2];
            float2 a3 = lds[I3];
            if (q != 1) {
                a1 = cmul(a1, w1);
                a2 = cmul(a2, w2);
                a3 = cmul(a3, w3);
            }
            float2 u0 = make_float2(a0.x + a2.x, a0.y + a2.y);
            float2 u1 = make_float2(a0.x - a2.x, a0.y - a2.y);
            float2 u2 = make_float2(a1.x + a3.x, a1.y + a3.y);
            float2 u3 = make_float2(a1.x - a3.x, a1.y - a3.y);
            lds[I0] = make_float2(u0.x + u2.x, u0.y + u2.y);
            lds[I2] = make_float2(u0.x - u2.x, u0.y - u2.y);
            if (SIGN < 0) {
                lds[I1] = make_float2(u1.x + u3.y, u1.y - u3.x);  // u1 - i*u3
                lds[I3] = make_float2(u1.x - u3.y, u1.y + u3.x);  // u1 + i*u3
            } else {
                lds[I1] = make_float2(u1.x - u3.y, u1.y + u3.x);
                lds[I3] = make_float2(u1.x + u3.y, u1.y - u3.x);
            }
            if (t == 6 && it != 3) {
                w1 = cmul(w1, wstep);
                w2 = cmul(w1, w1);
                w3 = cmul(w2, w1);
            }
        }
        __syncthreads();
    }
}

// shifts[b*16+e] = sigmoid(dot(tl[b,e,:], W) + b0) * NS
__global__ __launch_bounds__(64) void pos_kernel(const float* __restrict__ tl,
                                                 const float* __restrict__ W,
                                                 const float* __restrict__ bp,
                                                 float* __restrict__ shifts) {
    int bid = blockIdx.x;
    int t = threadIdx.x;
    const float* row = tl + (size_t)bid * 128;
    float p = row[t] * W[t] + row[t + 64] * W[t + 64];
#pragma unroll
    for (int off = 32; off > 0; off >>= 1) p += __shfl_down(p, off);
    if (t == 0) {
        float x = p + bp[0];
        float sig = 1.0f / (1.0f + expf(-x));
        shifts[bid] = sig * (float)NS;
    }
}

// Kernel A: one block per (b,e). Load stem (fused digit-reversal) -> FFT ->
// unpack rfft bins -> phase rotate -> write phased spectrum IN PLACE over the
// stem row. Unpack-loop phases advance by constant rotations per iteration
// (k += 1024): ph *= e^{-i*pi*s/16}, w *= e^{-i*pi/16} — 4 sincos total
// instead of 32 (drift over 16 cmuls ~1e-6, irrelevant vs 0.41 tolerance).
// Spectrum layout per row (16384 float2):
//   slot[0] = (DC, Nyquist*cos(pi*s)), slot[k] = X[k]*ph[k], k=1..M-1
__global__ __launch_bounds__(T2) void fft_phase_kernel(float* __restrict__ stems,
                                                       const float* __restrict__ shifts) {
    __shared__ float2 lds[LDS_ELEMS];
    const int tid = threadIdx.x;
    const int row = blockIdx.x;

    float* rowp = stems + (size_t)row * NS;
    const float4* src = (const float4*)rowp;
#pragma unroll
    for (int it = 0; it < (M / 2) / T2; ++it) {  // 8 float4 per thread
        int i = tid + it * T2;
        float4 v = src[i];
        lds[ldsIdx(rev4_14(2 * i))]     = make_float2(v.x, v.y);
        lds[ldsIdx(rev4_14(2 * i + 1))] = make_float2(v.z, v.w);
    }
    __syncthreads();

    fft_lds<-1>(lds, tid);

    const float s = shifts[row];
    const int si = (int)floorf(s);
    const float sf = s - (float)si;
    float2* spec = (float2*)rowp;

    float2 ph = shift_phase(tid, si, sf);          // exact at k=tid
    const float2 phstep = shift_phase(1024, si, sf);  // e^{-i*pi*s/16}, exact
    float2 w = wNS(tid);
    const float2 wstep = wNS(1024);                // e^{-i*pi/16}
#pragma unroll
    for (int t = 0; t < M / T2; ++t) {
        int k = tid + (t << 10);
        if (k == 0) {
            float2 z0 = lds[ldsIdx(0)];
            float X0 = z0.x + z0.y;   // DC, phase = 1
            float XM = z0.x - z0.y;   // Nyquist (real)
            float2 phM = shift_phase(M, si, sf);
            spec[0] = make_float2(X0, XM * phM.x);  // only Re survives irfft
        } else {
            float2 Zk = lds[ldsIdx(k)];
            float2 Zr = lds[ldsIdx(M - k)];
            float2 E = make_float2(0.5f * (Zk.x + Zr.x), 0.5f * (Zk.y - Zr.y));
            float2 O = make_float2(0.5f * (Zk.y + Zr.y), -0.5f * (Zk.x - Zr.x));
            float2 wo = cmul(w, O);
            float2 X = make_float2(E.x + wo.x, E.y + wo.y);
            spec[k] = cmul(X, ph);
        }
        ph = cmul(ph, phstep);
        w = cmul(w, wstep);
    }
}

// Kernel B1: full-grid elementwise sum of the 16 phased spectra per batch.
// Writes the batch spectrum into d_out (8 MB, exactly out_size).
__global__ __launch_bounds__(256) void reduce_kernel(const float4* __restrict__ stems,
                                                     float4* __restrict__ out) {
    int gid = blockIdx.x * 256 + threadIdx.x;   // 0 .. NB*NS/4-1
    int b = gid >> 13;                           // / (NS/4)
    int i = gid & (NS / 4 - 1);
    const float4* base = stems + (size_t)b * NEV * (NS / 4) + i;
    float4 s = base[0];
#pragma unroll
    for (int e = 1; e < NEV; ++e) {
        float4 v = base[(size_t)e * (NS / 4)];
        s.x += v.x; s.y += v.y; s.z += v.z; s.w += v.w;
    }
    out[gid] = s;
}

// Kernel B2: one block per batch. Load summed spectrum from d_out (fused
// digit-reversal), build packed Z' (rev-pair in-place trick, incremental w),
// inverse FFT, overwrite d_out with the real signal.
__global__ __launch_bounds__(T2) void inv_kernel(float* __restrict__ out) {
    __shared__ float2 lds[LDS_ELEMS];
    const int tid = threadIdx.x;
    const int b = blockIdx.x;

    const float4* src = (const float4*)(out + (size_t)b * NS);
#pragma unroll
    for (int it = 0; it < (M / 2) / T2; ++it) {  // i indexes float4 (2 slots)
        int i = tid + it * T2;
        float4 v = src[i];
        lds[ldsIdx(rev4_14(2 * i))]     = make_float2(v.x, v.y);
        lds[ldsIdx(rev4_14(2 * i + 1))] = make_float2(v.z, v.w);
    }
    __syncthreads();

    float2 w = wNS(tid);
    const float2 wstep = wNS(1024);  // e^{-i*pi/16}
#pragma unroll
    for (int t = 0; t < (M / 2) / T2; ++t) {
        int k = tid + (t << 10);
        if (k == 0) {
            float2 a0 = lds[ldsIdx(0)];  // (sum DC, sum Nyq)
            lds[ldsIdx(0)] = make_float2(0.5f * (a0.x + a0.y), 0.5f * (a0.x - a0.y));
            int rh = ldsIdx(rev4_14(M / 2));
            float2 ah = lds[rh];
            lds[rh] = make_float2(ah.x, -ah.y);  // Z'[M/2] = conj(A[M/2])
        } else {
            int pk = ldsIdx(rev4_14(k));
            int pm = ldsIdx(rev4_14(M - k));
            float2 a = lds[pk];
            float2 bb = lds[pm];
            // Z'[k] = E + i*O, E=(A[k]+conj(A[M-k]))/2, O=conj(w)*(A[k]-conj(A[M-k]))/2
            float2 E1 = make_float2(0.5f * (a.x + bb.x), 0.5f * (a.y - bb.y));
            float2 D1 = make_float2(0.5f * (a.x - bb.x), 0.5f * (a.y + bb.y));
            float2 wc = make_float2(w.x, -w.y);
            float2 O1 = cmul(wc, D1);
            float2 z1 = make_float2(E1.x - O1.y, E1.y + O1.x);
            float2 E2 = make_float2(E1.x, -E1.y);
            float2 D2 = make_float2(-D1.x, D1.y);
            float2 O2 = cmul(w, D2);
            O2 = make_float2(-O2.x, -O2.y);
            float2 z2 = make_float2(E2.x - O2.y, E2.y + O2.x);
            lds[pk] = z1;
            lds[pm] = z2;
        }
        w = cmul(w, wstep);
    }
    __syncthreads();

    fft_lds<1>(lds, tid);

    const float invM = 1.0f / (float)M;
    float4* dst = (float4*)(out + (size_t)b * NS);
#pragma unroll
    for (int it = 0; it < (NS / 4) / T2; ++it) {
        int i = tid + it * T2;
        float2 z0 = lds[ldsIdx(2 * i)];
        float2 z1 = lds[ldsIdx(2 * i + 1)];
        dst[i] = make_float4(z0.x * invM, z0.y * invM, z1.x * invM, z1.y * invM);
    }
}

extern "C" void kernel_launch(void* const* d_in, const int* in_sizes, int n_in,
                              void* d_out, int out_size, void* d_ws, size_t ws_size,
                              hipStream_t stream) {
    const float* time_latent = (const float*)d_in[0];
    float* stems = (float*)d_in[1];  // clobbered in place; harness restores per launch
    // d_in[2] = targets: unused by the reference output
    const float* W_pos = (const float*)d_in[3];
    const float* b_pos = (const float*)d_in[4];
    float* out = (float*)d_out;

    float* shifts = (float*)d_ws;  // 4 KB

    pos_kernel<<<NB * NEV, 64, 0, stream>>>(time_latent, W_pos, b_pos, shifts);
    fft_phase_kernel<<<NB * NEV, T2, 0, stream>>>(stems, shifts);
    reduce_kernel<<<(NB * NS / 4) / 256, 256, 0, stream>>>((const float4*)stems,
                                                           (float4*)out);
    inv_kernel<<<NB, T2, 0, stream>>>(out);
}

// Round 8
// 296.401 us; speedup vs baseline: 1.0485x; 1.0485x over previous
//
#include <hip/hip_runtime.h>
#include <math.h>

// Problem constants
#define NS      32768           // N_SAMPLES
#define M       16384           // NS/2, packed complex FFT length = 4^7
#define NEV     16
#define NB      64
#define T2      1024            // threads for FFT kernels (16 waves)

// LDS pad: break power-of-4 strides (incl. 1024/4096 from digit-reversal scatter)
__device__ __forceinline__ int ldsIdx(int i) { return i + (i >> 5) + (i >> 10); }
#define LDS_ELEMS (M + M / 32 + M / 1024)   // 16912 float2 = 135296 B < 160 KB

__device__ __forceinline__ float2 cmul(float2 a, float2 b) {
    return make_float2(a.x * b.x - a.y * b.y, a.x * b.y + a.y * b.x);
}

// reverse 7 base-4 digits (14 bits)
__device__ __forceinline__ int rev4_14(int i) {
    int r = 0;
#pragma unroll
    for (int d = 0; d < 7; ++d) { r = (r << 2) | (i & 3); i >>= 2; }
    return r;
}

// e^{-i*2*pi*k*s/NS}, s = si + sf (integer + fraction), exact integer mod
__device__ __forceinline__ float2 shift_phase(int k, int si, float sf) {
    unsigned ksi = ((unsigned)k * (unsigned)si) & (unsigned)(NS - 1);
    float total = (float)ksi + (float)k * sf;
    float f = total * (1.0f / (float)NS);
    f -= floorf(f);
    float ang = -6.28318530717958647692f * f;
    float sv, cv;
    __sincosf(ang, &sv, &cv);
    return make_float2(cv, sv);
}

// e^{-2*pi*i*k/NS}
__device__ __forceinline__ float2 wNS(int k) {
    float ang = (float)k * (-6.28318530717958647692f / (float)NS);
    float sv, cv;
    __sincosf(ang, &sv, &cv);
    return make_float2(cv, sv);
}

// cos/sin(2*pi*n/16), n = 0..3
__device__ __constant__ float R16C[4] = {1.0f, 0.92387953251128675613f,
                                         0.70710678118654752440f, 0.38268343236508977173f};
__device__ __constant__ float R16S[4] = {0.0f, 0.38268343236508977173f,
                                         0.70710678118654752440f, 0.92387953251128675613f};

// In-place radix-4 DIT FFT of M=4^7 points in LDS; input must already be
// digit-reversed, output natural order. SIGN=-1 forward, SIGN=+1 inverse
// (unscaled). Stages (0,1),(2,3),(4,5) are FUSED: each thread owns the
// 16-element set {base + l*q} (closed under both stages) and does two radix-4
// passes in registers per LDS round-trip. LDS round-trips 7->4, barriers 7->4.
// Stage-pair-2 twiddle: w'_n = ww * e^{SIGN*2pi*i*n/16} (1 sincos + const
// rotations; no loop-carried chains — round 7 showed those serialize).
template <int SIGN>
__device__ void fft_lds(float2* lds, int tid) {
    const float TP = (SIGN < 0) ? -6.28318530717958647692f
                                :  6.28318530717958647692f;
#pragma unroll
    for (int tp = 0; tp < 3; ++tp) {         // stage pairs (0,1),(2,3),(4,5)
        const int t = 2 * tp;
        const int q = 1 << (2 * t);          // 1, 16, 256
        const int j = tid & (q - 1);
        const int base = ((tid >> (2 * t)) << (2 * t + 4)) + j;
        float2 x[16];
#pragma unroll
        for (int l = 0; l < 16; ++l) x[l] = lds[ldsIdx(base + l * q)];

        // ---- stage t: butterflies (4m..4m+3), twiddle e^{TP*j/(4q)}^n ----
        float2 w1, w2, w3;
        if (tp > 0) {
            float sv, cv;
            __sincosf(TP * (float)j / (float)(4 * q), &sv, &cv);
            w1 = make_float2(cv, sv);
            w2 = cmul(w1, w1);
            w3 = cmul(w2, w1);
        }
#pragma unroll
        for (int m = 0; m < 4; ++m) {
            float2 a0 = x[4 * m], a1 = x[4 * m + 1], a2 = x[4 * m + 2], a3 = x[4 * m + 3];
            if (tp > 0) { a1 = cmul(a1, w1); a2 = cmul(a2, w2); a3 = cmul(a3, w3); }
            float2 u0 = make_float2(a0.x + a2.x, a0.y + a2.y);
            float2 u1 = make_float2(a0.x - a2.x, a0.y - a2.y);
            float2 u2 = make_float2(a1.x + a3.x, a1.y + a3.y);
            float2 u3 = make_float2(a1.x - a3.x, a1.y - a3.y);
            x[4 * m]     = make_float2(u0.x + u2.x, u0.y + u2.y);
            x[4 * m + 2] = make_float2(u0.x - u2.x, u0.y - u2.y);
            if (SIGN < 0) {
                x[4 * m + 1] = make_float2(u1.x + u3.y, u1.y - u3.x);  // u1 - i*u3
                x[4 * m + 3] = make_float2(u1.x - u3.y, u1.y + u3.x);  // u1 + i*u3
            } else {
                x[4 * m + 1] = make_float2(u1.x - u3.y, u1.y + u3.x);
                x[4 * m + 3] = make_float2(u1.x + u3.y, u1.y - u3.x);
            }
        }

        // ---- stage t+1: butterflies (n, n+4, n+8, n+12), j' = j + n*q ----
        float2 ww;
        if (tp > 0) {
            float sv, cv;
            __sincosf(TP * (float)j / (float)(16 * q), &sv, &cv);
            ww = make_float2(cv, sv);
        }
#pragma unroll
        for (int n = 0; n < 4; ++n) {
            float2 a0 = x[n], a1 = x[n + 4], a2 = x[n + 8], a3 = x[n + 12];
            if (!(tp == 0 && n == 0)) {
                float2 r = make_float2(R16C[n], (SIGN < 0) ? -R16S[n] : R16S[n]);
                float2 wp = (tp > 0) ? ((n > 0) ? cmul(ww, r) : ww) : r;
                float2 wp2 = cmul(wp, wp);
                float2 wp3 = cmul(wp2, wp);
                a1 = cmul(a1, wp);
                a2 = cmul(a2, wp2);
                a3 = cmul(a3, wp3);
            }
            float2 u0 = make_float2(a0.x + a2.x, a0.y + a2.y);
            float2 u1 = make_float2(a0.x - a2.x, a0.y - a2.y);
            float2 u2 = make_float2(a1.x + a3.x, a1.y + a3.y);
            float2 u3 = make_float2(a1.x - a3.x, a1.y - a3.y);
            x[n]      = make_float2(u0.x + u2.x, u0.y + u2.y);
            x[n + 8]  = make_float2(u0.x - u2.x, u0.y - u2.y);
            if (SIGN < 0) {
                x[n + 4]  = make_float2(u1.x + u3.y, u1.y - u3.x);
                x[n + 12] = make_float2(u1.x - u3.y, u1.y + u3.x);
            } else {
                x[n + 4]  = make_float2(u1.x - u3.y, u1.y + u3.x);
                x[n + 12] = make_float2(u1.x + u3.y, u1.y - u3.x);
            }
        }
#pragma unroll
        for (int l = 0; l < 16; ++l) lds[ldsIdx(base + l * q)] = x[l];
        __syncthreads();
    }

    // ---- single stage 6, q = 4096: per-iteration sincos (independent ILP) ----
    {
        const int q = 4096;
        const float c = TP / (float)(4 * q);
#pragma unroll
        for (int it = 0; it < (M / 4) / T2; ++it) {
            const int j = tid + it * T2;   // g == 0, base == j
            float sv, cv;
            __sincosf(c * (float)j, &sv, &cv);
            float2 w1 = make_float2(cv, sv);
            float2 w2 = cmul(w1, w1);
            float2 w3 = cmul(w2, w1);
            const int I0 = ldsIdx(j);
            const int I1 = ldsIdx(j + q);
            const int I2 = ldsIdx(j + 2 * q);
            const int I3 = ldsIdx(j + 3 * q);
            float2 a0 = lds[I0];
            float2 a1 = cmul(lds[I1], w1);
            float2 a2 = cmul(lds[I2], w2);
            float2 a3 = cmul(lds[I3], w3);
            float2 u0 = make_float2(a0.x + a2.x, a0.y + a2.y);
            float2 u1 = make_float2(a0.x - a2.x, a0.y - a2.y);
            float2 u2 = make_float2(a1.x + a3.x, a1.y + a3.y);
            float2 u3 = make_float2(a1.x - a3.x, a1.y - a3.y);
            lds[I0] = make_float2(u0.x + u2.x, u0.y + u2.y);
            lds[I2] = make_float2(u0.x - u2.x, u0.y - u2.y);
            if (SIGN < 0) {
                lds[I1] = make_float2(u1.x + u3.y, u1.y - u3.x);
                lds[I3] = make_float2(u1.x - u3.y, u1.y + u3.x);
            } else {
                lds[I1] = make_float2(u1.x - u3.y, u1.y + u3.x);
                lds[I3] = make_float2(u1.x + u3.y, u1.y - u3.x);
            }
        }
        __syncthreads();
    }
}

// shifts[b*16+e] = sigmoid(dot(tl[b,e,:], W) + b0) * NS
__global__ __launch_bounds__(64) void pos_kernel(const float* __restrict__ tl,
                                                 const float* __restrict__ W,
                                                 const float* __restrict__ bp,
                                                 float* __restrict__ shifts) {
    int bid = blockIdx.x;
    int t = threadIdx.x;
    const float* row = tl + (size_t)bid * 128;
    float p = row[t] * W[t] + row[t + 64] * W[t + 64];
#pragma unroll
    for (int off = 32; off > 0; off >>= 1) p += __shfl_down(p, off);
    if (t == 0) {
        float x = p + bp[0];
        float sig = 1.0f / (1.0f + expf(-x));
        shifts[bid] = sig * (float)NS;
    }
}

// Kernel A: one block per (b,e). Load stem (fused digit-reversal) -> FFT ->
// unpack rfft bins -> phase rotate -> write phased spectrum IN PLACE over the
// stem row. Per-iteration sincos (independent, good ILP — round 7 showed
// incremental-chain versions serialize).
// Spectrum layout per row (16384 float2):
//   slot[0] = (DC, Nyquist*cos(pi*s)), slot[k] = X[k]*ph[k], k=1..M-1
__global__ __launch_bounds__(T2) void fft_phase_kernel(float* __restrict__ stems,
                                                       const float* __restrict__ shifts) {
    __shared__ float2 lds[LDS_ELEMS];
    const int tid = threadIdx.x;
    const int row = blockIdx.x;

    float* rowp = stems + (size_t)row * NS;
    const float4* src = (const float4*)rowp;
#pragma unroll
    for (int it = 0; it < (M / 2) / T2; ++it) {  // 8 float4 per thread
        int i = tid + it * T2;
        float4 v = src[i];
        lds[ldsIdx(rev4_14(2 * i))]     = make_float2(v.x, v.y);
        lds[ldsIdx(rev4_14(2 * i + 1))] = make_float2(v.z, v.w);
    }
    __syncthreads();

    fft_lds<-1>(lds, tid);

    const float s = shifts[row];
    const int si = (int)floorf(s);
    const float sf = s - (float)si;
    float2* spec = (float2*)rowp;
#pragma unroll
    for (int t = 0; t < M / T2; ++t) {
        int k = tid + (t << 10);
        if (k == 0) {
            float2 z0 = lds[ldsIdx(0)];
            float X0 = z0.x + z0.y;   // DC, phase = 1
            float XM = z0.x - z0.y;   // Nyquist (real)
            float2 phM = shift_phase(M, si, sf);
            spec[0] = make_float2(X0, XM * phM.x);  // only Re survives irfft
        } else {
            float2 Zk = lds[ldsIdx(k)];
            float2 Zr = lds[ldsIdx(M - k)];
            float2 E = make_float2(0.5f * (Zk.x + Zr.x), 0.5f * (Zk.y - Zr.y));
            float2 O = make_float2(0.5f * (Zk.y + Zr.y), -0.5f * (Zk.x - Zr.x));
            float2 w = wNS(k);
            float2 wo = cmul(w, O);
            float2 X = make_float2(E.x + wo.x, E.y + wo.y);
            float2 ph = shift_phase(k, si, sf);
            spec[k] = cmul(X, ph);
        }
    }
}

// Kernel B1: full-grid elementwise sum of the 16 phased spectra per batch.
// Writes the batch spectrum into d_out (8 MB, exactly out_size).
__global__ __launch_bounds__(256) void reduce_kernel(const float4* __restrict__ stems,
                                                     float4* __restrict__ out) {
    int gid = blockIdx.x * 256 + threadIdx.x;   // 0 .. NB*NS/4-1
    int b = gid >> 13;                           // / (NS/4)
    int i = gid & (NS / 4 - 1);
    const float4* base = stems + (size_t)b * NEV * (NS / 4) + i;
    float4 s = base[0];
#pragma unroll
    for (int e = 1; e < NEV; ++e) {
        float4 v = base[(size_t)e * (NS / 4)];
        s.x += v.x; s.y += v.y; s.z += v.z; s.w += v.w;
    }
    out[gid] = s;
}

// Kernel B2: one block per batch. Load summed spectrum from d_out (fused
// digit-reversal), build packed Z' (rev-pair in-place trick), inverse FFT,
// overwrite d_out with the real signal.
__global__ __launch_bounds__(T2) void inv_kernel(float* __restrict__ out) {
    __shared__ float2 lds[LDS_ELEMS];
    const int tid = threadIdx.x;
    const int b = blockIdx.x;

    const float4* src = (const float4*)(out + (size_t)b * NS);
#pragma unroll
    for (int it = 0; it < (M / 2) / T2; ++it) {  // i indexes float4 (2 slots)
        int i = tid + it * T2;
        float4 v = src[i];
        lds[ldsIdx(rev4_14(2 * i))]     = make_float2(v.x, v.y);
        lds[ldsIdx(rev4_14(2 * i + 1))] = make_float2(v.z, v.w);
    }
    __syncthreads();

#pragma unroll
    for (int t = 0; t < (M / 2) / T2; ++t) {
        int k = tid + (t << 10);
        if (k == 0) {
            float2 a0 = lds[ldsIdx(0)];  // (sum DC, sum Nyq)
            lds[ldsIdx(0)] = make_float2(0.5f * (a0.x + a0.y), 0.5f * (a0.x - a0.y));
            int rh = ldsIdx(rev4_14(M / 2));
            float2 ah = lds[rh];
            lds[rh] = make_float2(ah.x, -ah.y);  // Z'[M/2] = conj(A[M/2])
        } else {
            int pk = ldsIdx(rev4_14(k));
            int pm = ldsIdx(rev4_14(M - k));
            float2 a = lds[pk];
            float2 bb = lds[pm];
            float2 w = wNS(k);
            // Z'[k] = E + i*O, E=(A[k]+conj(A[M-k]))/2, O=conj(w)*(A[k]-conj(A[M-k]))/2
            float2 E1 = make_float2(0.5f * (a.x + bb.x), 0.5f * (a.y - bb.y));
            float2 D1 = make_float2(0.5f * (a.x - bb.x), 0.5f * (a.y + bb.y));
            float2 wc = make_float2(w.x, -w.y);
            float2 O1 = cmul(wc, D1);
            float2 z1 = make_float2(E1.x - O1.y, E1.y + O1.x);
            float2 E2 = make_float2(E1.x, -E1.y);
            float2 D2 = make_float2(-D1.x, D1.y);
            float2 O2 = cmul(w, D2);
            O2 = make_float2(-O2.x, -O2.y);
            float2 z2 = make_float2(E2.x - O2.y, E2.y + O2.x);
            lds[pk] = z1;
            lds[pm] = z2;
        }
    }
    __syncthreads();

    fft_lds<1>(lds, tid);

    const float invM = 1.0f / (float)M;
    float4* dst = (float4*)(out + (size_t)b * NS);
#pragma unroll
    for (int it = 0; it < (NS / 4) / T2; ++it) {
        int i = tid + it * T2;
        float2 z0 = lds[ldsIdx(2 * i)];
        float2 z1 = lds[ldsIdx(2 * i + 1)];
        dst[i] = make_float4(z0.x * invM, z0.y * invM, z1.x * invM, z1.y * invM);
    }
}

extern "C" void kernel_launch(void* const* d_in, const int* in_sizes, int n_in,
                              void* d_out, int out_size, void* d_ws, size_t ws_size,
                              hipStream_t stream) {
    const float* time_latent = (const float*)d_in[0];
    float* stems = (float*)d_in[1];  // clobbered in place; harness restores per launch
    // d_in[2] = targets: unused by the reference output
    const float* W_pos = (const float*)d_in[3];
    const float* b_pos = (const float*)d_in[4];
    float* out = (float*)d_out;

    float* shifts = (float*)d_ws;  // 4 KB

    pos_kernel<<<NB * NEV, 64, 0, stream>>>(time_latent, W_pos, b_pos, shifts);
    fft_phase_kernel<<<NB * NEV, T2, 0, stream>>>(stems, shifts);
    reduce_kernel<<<(NB * NS / 4) / 256, 256, 0, stream>>>((const float4*)stems,
                                                           (float4*)out);
    inv_kernel<<<NB, T2, 0, stream>>>(out);
}